// Round 4
// baseline (264.911 us; speedup 1.0000x reference)
//
#include <hip/hip_runtime.h>

#define NR  8192
#define DIM 512
#define BM  128
#define NT  8   // K-tiles of 64 bf16 elements

typedef __attribute__((ext_vector_type(8))) short bf16x8;
typedef __attribute__((ext_vector_type(4))) float f32x4;
typedef unsigned short u16;
typedef unsigned int   u32;

// ---- async global->LDS, 16B per lane, wave-uniform LDS base ----
__device__ __forceinline__ void gload16(const void* g, void* l) {
    __builtin_amdgcn_global_load_lds((const __attribute__((address_space(1))) void*)g,
                                     (__attribute__((address_space(3))) void*)l,
                                     16, 0, 0);
}

// ================= fp32 -> bf16 + norms (of bf16-rounded values) =================
__global__ __launch_bounds__(256) void conv_bf16(const float* __restrict__ x,
                                                 const float* __restrict__ y,
                                                 u16* __restrict__ xb, u16* __restrict__ yb,
                                                 float* __restrict__ xn, float* __restrict__ yn) {
    int gw = (blockIdx.x * 256 + threadIdx.x) >> 6;
    int lane = threadIdx.x & 63;
    if (gw >= 2 * NR) return;
    int row = (gw < NR) ? gw : gw - NR;
    const float* src = (gw < NR) ? x : y;
    u16*   dst = (gw < NR) ? xb : yb;
    float* nrm = (gw < NR) ? xn : yn;

    const float4* p = (const float4*)(src + (size_t)row * DIM);
    float4 v0 = p[lane * 2], v1 = p[lane * 2 + 1];
    float vv[8] = {v0.x, v0.y, v0.z, v0.w, v1.x, v1.y, v1.z, v1.w};
    u16 us[8]; float s = 0.f;
    #pragma unroll
    for (int i = 0; i < 8; ++i) {
        u32 u = __float_as_uint(vv[i]);
        u16 b = (u16)((u + 0x7FFFu + ((u >> 16) & 1u)) >> 16);   // RNE fp32->bf16
        us[i] = b;
        float bf = __uint_as_float(((u32)b) << 16);
        s += bf * bf;
    }
    *(bf16x8*)(dst + (size_t)row * DIM + lane * 8) = *(const bf16x8*)us;
    #pragma unroll
    for (int off = 32; off; off >>= 1) s += __shfl_down(s, off, 64);
    if (lane == 0) nrm[row] = s;
}

__global__ void zero_kernel(double* acc) {
    if (threadIdx.x == 0 && blockIdx.x == 0) *acc = 0.0;
}

__global__ void finalize_kernel(const double* __restrict__ acc, float* __restrict__ out) {
    if (threadIdx.x == 0 && blockIdx.x == 0) {
        double n2 = (double)NR * (double)NR;
        out[0] = (float)(*acc / n2);
    }
}

// ================= bf16 MFMA fused pairwise kernel-sum, 2-phase double-buffered =================
// 1D grid of 8256 blocks: [0,2080) xx upper-tri, [2080,4160) yy upper-tri, [4160,8256) xy full
__global__ __launch_bounds__(256) void mmd_bf16(const u16* __restrict__ xb, const u16* __restrict__ yb,
                                                const float* __restrict__ xn, const float* __restrict__ yn,
                                                double* __restrict__ acc) {
    int f = blockIdx.x, z, bi, bj;
    if (f < 4160) {
        z = (f < 2080) ? 0 : 1;
        int t = (f < 2080) ? f : f - 2080;
        int r = (int)((sqrtf(8.f * t + 1.f) - 1.f) * 0.5f);
        while ((r + 1) * (r + 2) / 2 <= t) ++r;
        while (r * (r + 1) / 2 > t) --r;
        bi = t - r * (r + 1) / 2;   // bi <= bj
        bj = r;
    } else {
        z = 2; int t = f - 4160; bi = t >> 6; bj = t & 63;
    }
    const u16*   A  = (z == 1) ? yb : xb;
    const u16*   B  = (z == 0) ? xb : yb;
    const float* an = (z == 1) ? yn : xn;
    const float* bn = (z == 0) ? xn : yn;
    const float wgt = (z == 2) ? -2.f : ((bi == bj) ? 1.f : 2.f);
    const int bm = bi * BM, bnc = bj * BM;

    // [buf][A/B][row*64 + elem] : 2*2*128*64*2B = 65536 B exactly
    __shared__ __align__(16) u16 tiles[2][2][BM * 64];

    const int tid = threadIdx.x, w = tid >> 6, lane = tid & 63;
    const int wm = w >> 1, wn = w & 1;            // 2x2 wave grid, 64x64 out each
    const int srow = lane >> 3;                   // 0..7
    const int dslot = (lane & 7) ^ srow;          // pre-swizzled source 16B slot
    const int fr = lane & 15, kg = lane >> 4, sw = lane & 7;

    f32x4 acc4[4][4];
    #pragma unroll
    for (int i = 0; i < 4; ++i)
        #pragma unroll
        for (int j = 0; j < 4; ++j)
            acc4[i][j] = {0.f, 0.f, 0.f, 0.f};

    // prologue: stage K-tile 0 into buf 0
    #pragma unroll
    for (int q = 0; q < 4; ++q) {
        const int rb = w * 32 + q * 8;
        gload16(A + (size_t)(bm  + rb + srow) * DIM + dslot * 8, &tiles[0][0][rb * 64]);
        gload16(B + (size_t)(bnc + rb + srow) * DIM + dslot * 8, &tiles[0][1][rb * 64]);
    }
    __syncthreads();

    #pragma unroll
    for (int t = 0; t < NT; ++t) {
        const int cur = t & 1;
        // issue next-tile staging BEFORE compute; lands during MFMAs, drained by barrier
        if (t < NT - 1) {
            #pragma unroll
            for (int q = 0; q < 4; ++q) {
                const int rb = w * 32 + q * 8;
                gload16(A + (size_t)(bm  + rb + srow) * DIM + (t + 1) * 64 + dslot * 8,
                        &tiles[cur ^ 1][0][rb * 64]);
                gload16(B + (size_t)(bnc + rb + srow) * DIM + (t + 1) * 64 + dslot * 8,
                        &tiles[cur ^ 1][1][rb * 64]);
            }
        }
        // LDS -> fragments (swizzled reads), 2 x K=32 MFMA steps
        #pragma unroll
        for (int kk2 = 0; kk2 < 2; ++kk2) {
            const int c  = kk2 * 4 + kg;
            const int cs = (c ^ sw) * 8;
            bf16x8 af[4], bfv[4];
            #pragma unroll
            for (int fm = 0; fm < 4; ++fm)
                af[fm] = *(const bf16x8*)(&tiles[cur][0][(wm * 64 + fm * 16 + fr) * 64 + cs]);
            #pragma unroll
            for (int fn = 0; fn < 4; ++fn)
                bfv[fn] = *(const bf16x8*)(&tiles[cur][1][(wn * 64 + fn * 16 + fr) * 64 + cs]);
            #pragma unroll
            for (int fm = 0; fm < 4; ++fm)
                #pragma unroll
                for (int fn = 0; fn < 4; ++fn)
                    acc4[fm][fn] = __builtin_amdgcn_mfma_f32_16x16x32_bf16(af[fm], bfv[fn], acc4[fm][fn], 0, 0, 0);
        }
        __syncthreads();   // drains vmcnt (next tile staged) + retires this buf's reads
    }

    // epilogue: d = an + bn - 2*dot ; 3-bandwidth gaussian sum via t = exp(-d/12)
    float lsum = 0.f;
    #pragma unroll
    for (int fm = 0; fm < 4; ++fm) {
        const f32x4 anv = *(const f32x4*)(an + bm + wm * 64 + fm * 16 + kg * 4);
        #pragma unroll
        for (int fn = 0; fn < 4; ++fn) {
            const float bnv = bn[bnc + wn * 64 + fn * 16 + fr];
            #pragma unroll
            for (int j = 0; j < 4; ++j) {
                float d  = anv[j] + bnv - 2.0f * acc4[fm][fn][j];
                float t  = __expf(d * (-1.0f / 12.0f));
                float t2 = t * t, t3 = t2 * t;
                lsum += t2 + t3 + t3 * t3;   // bw3 + bw2 + bw1
            }
        }
    }
    #pragma unroll
    for (int off = 32; off; off >>= 1) lsum += __shfl_down(lsum, off, 64);

    // alias wsum onto dead tile memory (kept total static LDS at exactly 64 KiB);
    // the final K-loop barrier already retired all tile reads
    float* wsum = (float*)&tiles[0][0][0];
    if (lane == 0) wsum[w] = lsum;
    __syncthreads();
    if (tid == 0)
        atomicAdd(acc, (double)((wsum[0] + wsum[1] + wsum[2] + wsum[3]) * wgt));
}

// ================= launch =================
extern "C" void kernel_launch(void* const* d_in, const int* in_sizes, int n_in,
                              void* d_out, int out_size, void* d_ws, size_t ws_size,
                              hipStream_t stream) {
    const float* x = (const float*)d_in[0];
    const float* y = (const float*)d_in[1];
    float* out = (float*)d_out;
    char* ws = (char*)d_ws;

    const size_t bBytes = (size_t)NR * DIM * 2;      // 8 MiB each
    u16*   xb = (u16*)ws;
    u16*   yb = (u16*)(ws + bBytes);
    float* xn = (float*)(ws + 2 * bBytes);
    float* yn = (float*)(ws + 2 * bBytes + (size_t)NR * 4);
    double* acc = (double*)(ws + 2 * bBytes + 2 * (size_t)NR * 4);

    zero_kernel<<<1, 64, 0, stream>>>(acc);
    conv_bf16<<<(2 * NR) / 4, 256, 0, stream>>>(x, y, xb, yb, xn, yn);
    mmd_bf16<<<8256, 256, 0, stream>>>(xb, yb, xn, yn, acc);
    finalize_kernel<<<1, 64, 0, stream>>>(acc, out);
}

// Round 5
// 195.211 us; speedup vs baseline: 1.3570x; 1.3570x over previous
//
#include <hip/hip_runtime.h>

#define NR  8192
#define DIM 512
#define BM  256          // square tile
#define BK  64
#define NT  8            // DIM / BK

typedef __attribute__((ext_vector_type(8))) short bf16x8;
typedef __attribute__((ext_vector_type(4))) float f32x4;
typedef unsigned short u16;
typedef unsigned int   u32;

__device__ __forceinline__ void gload16(const void* g, void* l) {
    __builtin_amdgcn_global_load_lds((const __attribute__((address_space(1))) void*)g,
                                     (__attribute__((address_space(3))) void*)l,
                                     16, 0, 0);
}

// ================= fp32 -> bf16 + norms (of bf16-rounded values) =================
__global__ __launch_bounds__(256) void conv_bf16(const float* __restrict__ x,
                                                 const float* __restrict__ y,
                                                 u16* __restrict__ xb, u16* __restrict__ yb,
                                                 float* __restrict__ xn, float* __restrict__ yn) {
    int gw = (blockIdx.x * 256 + threadIdx.x) >> 6;
    int lane = threadIdx.x & 63;
    if (gw >= 2 * NR) return;
    int row = (gw < NR) ? gw : gw - NR;
    const float* src = (gw < NR) ? x : y;
    u16*   dst = (gw < NR) ? xb : yb;
    float* nrm = (gw < NR) ? xn : yn;

    const float4* p = (const float4*)(src + (size_t)row * DIM);
    float4 v0 = p[lane * 2], v1 = p[lane * 2 + 1];
    float vv[8] = {v0.x, v0.y, v0.z, v0.w, v1.x, v1.y, v1.z, v1.w};
    u16 us[8]; float s = 0.f;
    #pragma unroll
    for (int i = 0; i < 8; ++i) {
        u32 u = __float_as_uint(vv[i]);
        u16 b = (u16)((u + 0x7FFFu + ((u >> 16) & 1u)) >> 16);   // RNE fp32->bf16
        us[i] = b;
        float bf = __uint_as_float(((u32)b) << 16);
        s += bf * bf;
    }
    *(bf16x8*)(dst + (size_t)row * DIM + lane * 8) = *(const bf16x8*)us;
    #pragma unroll
    for (int off = 32; off; off >>= 1) s += __shfl_down(s, off, 64);
    if (lane == 0) nrm[row] = s;
}

__global__ void zero_kernel(double* acc) {
    if (threadIdx.x == 0 && blockIdx.x == 0) *acc = 0.0;
}

__global__ void finalize_kernel(const double* __restrict__ acc, float* __restrict__ out) {
    if (threadIdx.x == 0 && blockIdx.x == 0) {
        double n2 = (double)NR * (double)NR;
        out[0] = (float)(*acc / n2);
    }
}

// ================= 256^2-tile, 8-wave, counted-vmcnt MFMA kernel =================
// logical grid 2080: [0,528) xx upper-tri, [528,1056) yy upper-tri, [1056,2080) xy (weight -2)
__global__ __launch_bounds__(512, 2) void mmd_bf16(const u16* __restrict__ xb, const u16* __restrict__ yb,
                                                   const float* __restrict__ xn, const float* __restrict__ yn,
                                                   double* __restrict__ acc) {
    // T1: XCD-aware swizzle (2080 % 8 == 0 -> simple bijective form)
    int f = (blockIdx.x & 7) * 260 + (blockIdx.x >> 3);
    int z, bi, bj;
    if (f < 1056) {
        z = (f < 528) ? 0 : 1;
        int t = (f < 528) ? f : f - 528;
        int r = (int)((sqrtf(8.f * t + 1.f) - 1.f) * 0.5f);
        while ((r + 1) * (r + 2) / 2 <= t) ++r;
        while (r * (r + 1) / 2 > t) --r;
        bi = t - r * (r + 1) / 2;   // bi <= bj
        bj = r;
    } else {
        z = 2; int t = f - 1056; bi = t >> 5; bj = t & 31;
    }
    const u16*   A  = (z == 1) ? yb : xb;
    const u16*   B  = (z == 0) ? xb : yb;
    const float* an = (z == 1) ? yn : xn;
    const float* bn = (z == 0) ? xn : yn;
    const float wgt = (z == 2) ? -2.f : ((bi == bj) ? 1.f : 2.f);
    const int bm = bi * BM, bnc = bj * BM;

    // double-buffered A,B tiles: 2 * 2 * 256*64 * 2B = 128 KiB
    __shared__ __align__(16) u16 Al[2][BM * BK];
    __shared__ __align__(16) u16 Bl[2][BM * BK];

    const int tid = threadIdx.x, w = tid >> 6, lane = tid & 63;
    const int wm = w >> 2, wn = w & 3;            // 2x4 wave grid; per-wave 128x64 out
    const int srow = lane >> 3;                   // 0..7
    const int dslot = (lane & 7) ^ srow;          // pre-swizzled source 16B slot
    const int fr = lane & 15, kg = lane >> 4;

    // lane-constant LDS element offsets
    int raO[8], rbO[4];
    #pragma unroll
    for (int fm = 0; fm < 8; ++fm) raO[fm] = (wm * 128 + fm * 16 + fr) * BK;
    #pragma unroll
    for (int fn = 0; fn < 4; ++fn) rbO[fn] = (wn * 64 + fn * 16 + fr) * BK;
    const int s0 = ((kg)     ^ (lane & 7)) * 8;   // kstep0 swizzled slot offset (elems)
    const int s1 = ((4 + kg) ^ (lane & 7)) * 8;   // kstep1

    f32x4 acc4[8][4];
    #pragma unroll
    for (int i = 0; i < 8; ++i)
        #pragma unroll
        for (int j = 0; j < 4; ++j)
            acc4[i][j] = {0.f, 0.f, 0.f, 0.f};

    // staging helper offsets: wave w covers rows w*32 + q*8 + srow (q=0..3), 8 waves -> 256 rows
    const size_t aRow = (size_t)(bm  + w * 32 + srow) * DIM + dslot * 8;
    const size_t bRow = (size_t)(bnc + w * 32 + srow) * DIM + dslot * 8;

#define STAGE(kt, buf)                                                              \
    {                                                                               \
        _Pragma("unroll")                                                           \
        for (int q = 0; q < 4; ++q) {                                               \
            const int rb_ = w * 32 + q * 8;                                         \
            gload16(A + aRow + (size_t)q * 8 * DIM + (kt) * BK, &Al[buf][rb_ * BK]);\
            gload16(B + bRow + (size_t)q * 8 * DIM + (kt) * BK, &Bl[buf][rb_ * BK]);\
        }                                                                           \
    }

    // prologue: stage tiles 0 and 1; wait tile 0 (tile 1 stays in flight)
    STAGE(0, 0)
    STAGE(1, 1)
    asm volatile("s_waitcnt vmcnt(8)" ::: "memory");
    __builtin_amdgcn_s_barrier();

    #pragma unroll
    for (int kt = 0; kt < NT; ++kt) {
        const int cur = kt & 1;
        const u16* Ab = &Al[cur][0];
        const u16* Bb = &Bl[cur][0];

        // ---- phase 0: kstep0 frags + 32 MFMA ----
        {
            bf16x8 af[8], bf[4];
            #pragma unroll
            for (int fm = 0; fm < 8; ++fm) af[fm] = *(const bf16x8*)(Ab + raO[fm] + s0);
            #pragma unroll
            for (int fn = 0; fn < 4; ++fn) bf[fn] = *(const bf16x8*)(Bb + rbO[fn] + s0);
            __builtin_amdgcn_s_setprio(1);
            #pragma unroll
            for (int fm = 0; fm < 8; ++fm)
                #pragma unroll
                for (int fn = 0; fn < 4; ++fn)
                    acc4[fm][fn] = __builtin_amdgcn_mfma_f32_16x16x32_bf16(af[fm], bf[fn], acc4[fm][fn], 0, 0, 0);
            __builtin_amdgcn_s_setprio(0);
        }
        // ---- phase 1: kstep1 frags + 32 MFMA ----
        {
            bf16x8 af[8], bf[4];
            #pragma unroll
            for (int fm = 0; fm < 8; ++fm) af[fm] = *(const bf16x8*)(Ab + raO[fm] + s1);
            #pragma unroll
            for (int fn = 0; fn < 4; ++fn) bf[fn] = *(const bf16x8*)(Bb + rbO[fn] + s1);
            __builtin_amdgcn_s_setprio(1);
            #pragma unroll
            for (int fm = 0; fm < 8; ++fm)
                #pragma unroll
                for (int fn = 0; fn < 4; ++fn)
                    acc4[fm][fn] = __builtin_amdgcn_mfma_f32_16x16x32_bf16(af[fm], bf[fn], acc4[fm][fn], 0, 0, 0);
            __builtin_amdgcn_s_setprio(0);
        }

        if (kt + 1 < NT) {
            // all reads of buf[cur] retired (lgkm waits precede the MFMAs above);
            // barrier so no wave overwrites buf[cur] while others still read it
            asm volatile("s_waitcnt lgkmcnt(0)" ::: "memory");
            __builtin_amdgcn_s_barrier();
            if (kt + 2 < NT) {
                STAGE(kt + 2, cur)                         // overwrite just-freed buffer
                asm volatile("s_waitcnt vmcnt(8)" ::: "memory");  // tile kt+1 landed; kt+2 in flight
            } else {
                asm volatile("s_waitcnt vmcnt(0)" ::: "memory");  // last tile: drain
            }
            __builtin_amdgcn_s_barrier();                  // tile kt+1 visible to all waves
        }
    }

    // ---- epilogue: d = an + bn - 2*dot ; 3-bandwidth gaussian sum via t = exp(-d/12) ----
    float lsum = 0.f;
    #pragma unroll
    for (int fm = 0; fm < 8; ++fm) {
        const f32x4 anv = *(const f32x4*)(an + bm + wm * 128 + fm * 16 + kg * 4);
        #pragma unroll
        for (int fn = 0; fn < 4; ++fn) {
            const float bnv = bn[bnc + wn * 64 + fn * 16 + fr];
            #pragma unroll
            for (int j = 0; j < 4; ++j) {
                float d  = anv[j] + bnv - 2.0f * acc4[fm][fn][j];
                float t  = __expf(d * (-1.0f / 12.0f));
                float t2 = t * t, t3 = t2 * t;
                lsum += t2 + t3 + t3 * t3;   // bw3 + bw2 + bw1
            }
        }
    }
    #pragma unroll
    for (int off = 32; off; off >>= 1) lsum += __shfl_down(lsum, off, 64);

    // alias wsum onto buf0 A-tile (all reads long since retired; kt=7 read buf1)
    float* wsum = (float*)&Al[0][0];
    if (lane == 0) wsum[w] = lsum;
    __syncthreads();
    if (tid == 0) {
        float bs = 0.f;
        #pragma unroll
        for (int i = 0; i < 8; ++i) bs += wsum[i];
        atomicAdd(acc, (double)(bs * wgt));
    }
#undef STAGE
}

// ================= launch =================
extern "C" void kernel_launch(void* const* d_in, const int* in_sizes, int n_in,
                              void* d_out, int out_size, void* d_ws, size_t ws_size,
                              hipStream_t stream) {
    const float* x = (const float*)d_in[0];
    const float* y = (const float*)d_in[1];
    float* out = (float*)d_out;
    char* ws = (char*)d_ws;

    const size_t bBytes = (size_t)NR * DIM * 2;      // 8 MiB each
    u16*   xb = (u16*)ws;
    u16*   yb = (u16*)(ws + bBytes);
    float* xn = (float*)(ws + 2 * bBytes);
    float* yn = (float*)(ws + 2 * bBytes + (size_t)NR * 4);
    double* acc = (double*)(ws + 2 * bBytes + 2 * (size_t)NR * 4);

    zero_kernel<<<1, 64, 0, stream>>>(acc);
    conv_bf16<<<(2 * NR) / 4, 256, 0, stream>>>(x, y, xb, yb, xn, yn);
    mmd_bf16<<<2080, 512, 0, stream>>>(xb, yb, xn, yn, acc);
    finalize_kernel<<<1, 64, 0, stream>>>(acc, out);
}